// Round 9
// baseline (151.415 us; speedup 1.0000x reference)
//
#include <hip/hip_runtime.h>

typedef unsigned short u16;
typedef float f32x4 __attribute__((ext_vector_type(4)));
typedef __bf16 bf16x8 __attribute__((ext_vector_type(8)));
typedef unsigned short u16x8 __attribute__((ext_vector_type(8)));
typedef unsigned short u16x4 __attribute__((ext_vector_type(4)));

#define DEV static __device__ __forceinline__

DEV u16 f2bf(float f) {
  unsigned int u = __float_as_uint(f);
  u += 0x7FFFu + ((u >> 16) & 1u);   // round-to-nearest-even
  return (u16)(u >> 16);
}
DEV float bf2f(u16 h) { return __uint_as_float(((unsigned int)h) << 16); }

// async global->LDS, 16B per lane. LDS dest = wave-uniform base + lane*16.
DEV void gload_lds16(const void* g, void* l) {
  __builtin_amdgcn_global_load_lds(
      (__attribute__((address_space(1))) void*)(unsigned long long)g,
      (__attribute__((address_space(3))) void*)l, 16, 0, 0);
}

// ---------------------------------------------------------------------------
// K0b: convert w_qkv fp32 -> bf16 (plain row-major [576][192])
__global__ __launch_bounds__(256) void convert_w_kernel(
    const float* __restrict__ in, u16* __restrict__ out, int n) {
  int i = blockIdx.x * 256 + threadIdx.x;
  if (i < n) out[i] = f2bf(in[i]);
}

// ---------------------------------------------------------------------------
// B^T GEMM, big-LDS single-shot variant. C[j][m] = sum_k A^T[m][k]*B[j][k],
// K=192. 512 threads (8 waves, 4m x 2n). BM=128 px, BN=192 channels.
// LDS: sA [128][384B] 48 KB + sB [192][384B] 72 KB = 120 KB -> 1 block/CU.
// ONE barrier total: stage A (fused transpose+convert, swizzled ds_write)
// and B (72 gload_lds chunks from the L2-resident weight panel), barrier,
// then 72 MFMA/wave with only compiler-scheduled lgkmcnt — no per-tile sync.
// grid = (128 m-tiles, NJG j-groups, 4 batches).
template <bool IN_F32, bool OUT_BF16>
__global__ __launch_bounds__(512, 2) void gemm_bt_kernel(
    const void* __restrict__ Av, const u16* __restrict__ B,
    void* __restrict__ Cv, size_t aBatch, size_t bBatch, size_t cBatch,
    int ldC) {
  __shared__ __align__(16) char smem[122880];
  char* sA = smem;            // [128][384B] content-swizzled
  char* sB = smem + 49152;    // [192][384B] content-swizzled

  const int tid = threadIdx.x, wave = tid >> 6, lane = tid & 63;
  const int m0 = blockIdx.x * 128;
  const int jg = blockIdx.y, b = blockIdx.z;

  // ---- stage B panel: rows jg*192 .. jg*192+191, 72 KB, 9 chunks/wave
  const char* Bbase = (const char*)(B + (size_t)b * bBatch);
#pragma unroll
  for (int i = 0; i < 9; ++i) {
    const int c = i * 8 + wave;
    const int d = c * 1024 + lane * 16;
    const int row = d / 384, inrow = d - row * 384;
    gload_lds16(Bbase + (size_t)(jg * 192 + row) * 384 +
                    (inrow ^ ((row & 7) << 4)),
                sB + c * 1024);
  }

  // ---- stage A: global->reg, transpose+convert, swizzled ds_write
  if (IN_F32) {
    const float* Xb = (const float*)Av + (size_t)b * aBatch + m0;
    const int cbl = tid & 15, iq = tid >> 4;  // 16 c-quads x 32 n-quads
    f32x4 vaf[3][4];
#pragma unroll
    for (int p = 0; p < 3; ++p)
#pragma unroll
      for (int r = 0; r < 4; ++r)
        vaf[p][r] = *(const f32x4*)(Xb + (size_t)((p * 16 + cbl) * 4 + r) *
                                             16384 + iq * 4);
#pragma unroll
    for (int p = 0; p < 3; ++p) {
      const int cb = p * 16 + cbl;
#pragma unroll
      for (int j = 0; j < 4; ++j) {
        const int n = iq * 4 + j;
        u16x4 col;
        col[0] = f2bf(vaf[p][0][j]);
        col[1] = f2bf(vaf[p][1][j]);
        col[2] = f2bf(vaf[p][2][j]);
        col[3] = f2bf(vaf[p][3][j]);
        *(u16x4*)(sA + n * 384 + ((cb * 8) ^ ((n & 7) << 4))) = col;
      }
    }
  } else {
    const u16* Vb = (const u16*)Av + (size_t)b * aBatch + m0;
#pragma unroll
    for (int p = 0; p < 2; ++p) {
      const int task = p * 512 + tid;  // 48 c-quads x 16 n-octs = 768 tasks
      if (task < 768) {
        const int cb = task >> 4, io = task & 15;
        u16x8 v[4];
#pragma unroll
        for (int r = 0; r < 4; ++r)
          v[r] = *(const u16x8*)(Vb + (size_t)(cb * 4 + r) * 16384 + io * 8);
#pragma unroll
        for (int j = 0; j < 8; ++j) {
          const int n = io * 8 + j;
          u16x4 col;
          col[0] = v[0][j];
          col[1] = v[1][j];
          col[2] = v[2][j];
          col[3] = v[3][j];
          *(u16x4*)(sA + n * 384 + ((cb * 8) ^ ((n & 7) << 4))) = col;
        }
      }
    }
  }
  asm volatile("s_waitcnt vmcnt(0) lgkmcnt(0)" ::: "memory");
  __syncthreads();  // the only barrier

  const int wm = wave >> 1, wn = wave & 1;  // 4m x 2n wave grid
  const int l15 = lane & 15, lg = lane >> 4;
  const int swm = (l15 & 7) << 4;

  // ---- A fragments hoisted (wave tile: 32 px x 96 ch)
  bf16x8 af[2][6];
#pragma unroll
  for (int mi = 0; mi < 2; ++mi)
#pragma unroll
    for (int ks = 0; ks < 6; ++ks)
      af[mi][ks] = *(const bf16x8*)(sA + (wm * 32 + mi * 16 + l15) * 384 +
                                    ((ks * 64 + lg * 16) ^ swm));

  f32x4 acc[2][6];
#pragma unroll
  for (int mi = 0; mi < 2; ++mi)
#pragma unroll
    for (int nj = 0; nj < 6; ++nj) acc[mi][nj] = (f32x4){0.f, 0.f, 0.f, 0.f};

#pragma unroll
  for (int ks = 0; ks < 6; ++ks) {
    bf16x8 bfv[6];
#pragma unroll
    for (int nj = 0; nj < 6; ++nj)
      bfv[nj] = *(const bf16x8*)(sB + (wn * 96 + nj * 16 + l15) * 384 +
                                 ((ks * 64 + lg * 16) ^ swm));
#pragma unroll
    for (int mi = 0; mi < 2; ++mi)
#pragma unroll
      for (int nj = 0; nj < 6; ++nj)
        acc[mi][nj] = __builtin_amdgcn_mfma_f32_16x16x32_bf16(
            af[mi][ks], bfv[nj], acc[mi][nj], 0, 0, 0);
  }

  // ---- stores (once)
  const int orow0 = jg * 192 + wn * 96;
  if (OUT_BF16) {
    u16* Cb = (u16*)Cv + (size_t)b * cBatch;
#pragma unroll
    for (int mi = 0; mi < 2; ++mi)
#pragma unroll
      for (int nj = 0; nj < 6; ++nj) {
        u16x4 ov;
#pragma unroll
        for (int r = 0; r < 4; ++r) ov[r] = f2bf(acc[mi][nj][r]);
        *(u16x4*)(Cb + (size_t)(orow0 + nj * 16 + l15) * ldC + m0 + wm * 32 +
                  mi * 16 + lg * 4) = ov;
      }
  } else {
    float* Cb = (float*)Cv + (size_t)b * cBatch;
#pragma unroll
    for (int mi = 0; mi < 2; ++mi)
#pragma unroll
      for (int nj = 0; nj < 6; ++nj)
        *(f32x4*)(Cb + (size_t)(orow0 + nj * 16 + l15) * ldC + m0 + wm * 32 +
                  mi * 16 + lg * 4) = acc[mi][nj];
  }
}

// ---------------------------------------------------------------------------
// Depthwise 3x3 (pad 1), in-place on bf16 [b][576][128][128]; per-channel
// sum-of-squares for the q/k L2 norms. One block per (b, channel).
__global__ __launch_bounds__(256) void dwconv_kernel(
    u16* __restrict__ qkv, const float* __restrict__ wdw,
    float* __restrict__ sq) {
  __shared__ u16 img[16384];  // full 128x128 channel, 32 KB
  __shared__ float red[4];
  const int o = blockIdx.x, b = blockIdx.y;
  const size_t base = ((size_t)b * 576 + o) * 16384;
  const int tid = threadIdx.x, wave = tid >> 6, lane = tid & 63;
#pragma unroll
  for (int i = 0; i < 8; ++i) {
    const int off = (i * 4 + wave) * 1024;
    gload_lds16((const char*)qkv + base * 2 + off + lane * 16, (char*)img + off);
  }
  asm volatile("s_waitcnt vmcnt(0)" ::: "memory");
  __syncthreads();
  float w[9];
#pragma unroll
  for (int j = 0; j < 9; ++j) w[j] = wdw[o * 9 + j];
  float sqacc = 0.f;
  for (int it = 0; it < 8; ++it) {
    const int chunk = it * 256 + tid;  // 2048 chunks of 8 px
    const int px0 = chunk * 8;
    const int y = px0 >> 7, x0 = px0 & 127;
    float acc[8];
#pragma unroll
    for (int j = 0; j < 8; ++j) acc[j] = 0.f;
#pragma unroll
    for (int dy = -1; dy <= 1; ++dy) {
      const int yy = y + dy;
      float v[10];
      if (yy >= 0 && yy <= 127) {
        const u16* rowp = img + yy * 128 + x0;
        u16x8 m = *(const u16x8*)rowp;
#pragma unroll
        for (int j = 0; j < 8; ++j) v[j + 1] = bf2f(m[j]);
        v[0] = (x0 > 0) ? bf2f(rowp[-1]) : 0.f;
        v[9] = (x0 < 120) ? bf2f(rowp[8]) : 0.f;
      } else {
#pragma unroll
        for (int j = 0; j < 10; ++j) v[j] = 0.f;
      }
      const float w0 = w[(dy + 1) * 3], w1 = w[(dy + 1) * 3 + 1],
                  w2 = w[(dy + 1) * 3 + 2];
#pragma unroll
      for (int j = 0; j < 8; ++j) acc[j] += w0 * v[j] + w1 * v[j + 1] + w2 * v[j + 2];
    }
    u16x8 ov;
#pragma unroll
    for (int j = 0; j < 8; ++j) {
      sqacc += acc[j] * acc[j];
      ov[j] = f2bf(acc[j]);
    }
    *(u16x8*)(qkv + base + px0) = ov;  // in-place: all reads came from LDS
  }
#pragma unroll
  for (int s = 32; s > 0; s >>= 1) sqacc += __shfl_xor(sqacc, s, 64);
  if (lane == 0) red[wave] = sqacc;
  __syncthreads();
  if (tid == 0) sq[b * 576 + o] = red[0] + red[1] + red[2] + red[3];
}

// ---------------------------------------------------------------------------
// Gram: G_partial[c][d] = sum_n q[c][n]*k[d][n] over a 512-n block (4 waves x
// 128 n each, reduced in-block through LDS). Tile content XOR-swizzled.
// grid (32 chunk-groups, 16 bh); partial[bh][pos][chunk32].
__global__ __launch_bounds__(256) void gram_kernel(
    const u16* __restrict__ qkv, float* __restrict__ partial) {
  __shared__ u16 tiles[4 * 3072];   // per-wave [96][32] bf16 (q 0-47, k 48-95)
  __shared__ float red[4 * 2304];   // per-wave gram copies for in-block reduce
  const int bh = blockIdx.y, b = bh >> 2, h = bh & 3;
  const int g = blockIdx.x;                  // chunk 0..31
  const int wave = threadIdx.x >> 6, lane = threadIdx.x & 63;
  const int n0 = g * 512 + wave * 128;
  const u16* qb = qkv + ((size_t)b * 576 + h * 48) * 16384;
  const u16* kb = qb + (size_t)192 * 16384;
  char* tl = (char*)(tiles + wave * 3072);
  const int l15 = lane & 15, lg = lane >> 4;
  const int swz = (l15 & 3) << 4;
  f32x4 acc[3][3];
#pragma unroll
  for (int i = 0; i < 3; ++i)
#pragma unroll
    for (int j = 0; j < 3; ++j) acc[i][j] = (f32x4){0.f, 0.f, 0.f, 0.f};

  for (int ks = 0; ks < 4; ++ks) {
    const int nn = n0 + ks * 32;
    asm volatile("s_waitcnt lgkmcnt(0)" ::: "memory");
#pragma unroll
    for (int i = 0; i < 6; ++i) {
      const int flat = i * 1024 + lane * 16;
      const int row = flat >> 6, colb = flat & 63;
      const u16* src = (row < 48) ? (qb + (size_t)row * 16384 + nn)
                                  : (kb + (size_t)(row - 48) * 16384 + nn);
      gload_lds16((const char*)src + (colb ^ ((row & 3) << 4)), tl + i * 1024);
    }
    asm volatile("s_waitcnt vmcnt(0)" ::: "memory");
    bf16x8 qf[3], kf[3];
#pragma unroll
    for (int f = 0; f < 3; ++f) {
      qf[f] = *(const bf16x8*)(tl + (f * 16 + l15) * 64 + ((lg * 16) ^ swz));
      kf[f] = *(const bf16x8*)(tl + (48 + f * 16 + l15) * 64 + ((lg * 16) ^ swz));
    }
#pragma unroll
    for (int i = 0; i < 3; ++i)
#pragma unroll
      for (int j = 0; j < 3; ++j)
        acc[i][j] = __builtin_amdgcn_mfma_f32_16x16x32_bf16(qf[i], kf[j],
                                                            acc[i][j], 0, 0, 0);
  }
  // in-block reduce over the 4 waves
  {
    float* rw = red + wave * 2304;
#pragma unroll
    for (int i = 0; i < 3; ++i)
#pragma unroll
      for (int j = 0; j < 3; ++j)
#pragma unroll
        for (int r = 0; r < 4; ++r)
          rw[(i * 16 + lg * 4 + r) * 48 + (j * 16 + l15)] = acc[i][j][r];
  }
  __syncthreads();
#pragma unroll
  for (int it = 0; it < 9; ++it) {
    const int p = it * 256 + threadIdx.x;
    const float s = red[p] + red[2304 + p] + red[4608 + p] + red[6912 + p];
    partial[((size_t)bh * 2304 + p) * 32 + g] = s;
  }
}

// ---------------------------------------------------------------------------
// Wide reduction of gram partials: G[bh*2304+p] = sum over 32 chunks.
__global__ __launch_bounds__(256) void reduce_partial_kernel(
    const float* __restrict__ partial, float* __restrict__ G) {
  const int idx = blockIdx.x * 256 + threadIdx.x;  // 0..36863
  const f32x4* pp = (const f32x4*)(partial + (size_t)idx * 32);
  const f32x4 a = (pp[0] + pp[1]) + (pp[2] + pp[3]) +
                  (pp[4] + pp[5]) + (pp[6] + pp[7]);
  G[idx] = a.x + a.y + a.z + a.w;
}

// ---------------------------------------------------------------------------
// Normalize, softmax, fold attn into projection (plain row-major Weff out).
__global__ __launch_bounds__(256) void softmax_weff_kernel(
    const float* __restrict__ Gin, const float* __restrict__ sq,
    const float* __restrict__ temp, const float* __restrict__ wproj,
    u16* __restrict__ weff) {
  __shared__ float G[2304];        // gram -> attn (in place)
  __shared__ float wp[192 * 49];   // wproj slice, pad 49 (odd bank stride)
  __shared__ float nq[48], nk[48];
  const int bh = blockIdx.x, b = bh >> 2, h = bh & 3;
  const int tid = threadIdx.x;
#pragma unroll
  for (int it = 0; it < 36; ++it) {  // load wproj [192][h*48 .. h*48+48)
    const int j = it * 256 + tid;
    const int o = j / 48, c = j - o * 48;
    wp[o * 49 + c] = wproj[o * 192 + h * 48 + c];
  }
#pragma unroll
  for (int it = 0; it < 9; ++it) {
    const int p = it * 256 + tid;
    G[p] = Gin[(size_t)bh * 2304 + p];
  }
  if (tid < 48) {
    nq[tid] = fmaxf(sqrtf(sq[b * 576 + h * 48 + tid]), 1e-12f);
    nk[tid] = fmaxf(sqrtf(sq[b * 576 + 192 + h * 48 + tid]), 1e-12f);
  }
  __syncthreads();
  if (tid < 48) {  // row softmax (48 rows)
    const int r = tid;
    const float inq = temp[h] / nq[r];
    float L[48];
    float mx = -3.4e38f;
#pragma unroll 4
    for (int d = 0; d < 48; ++d) {
      const float v = G[r * 48 + d] * inq / nk[d];
      L[d] = v;
      mx = fmaxf(mx, v);
    }
    float s = 0.f;
#pragma unroll 4
    for (int d = 0; d < 48; ++d) {
      const float e = __expf(L[d] - mx);
      L[d] = e;
      s += e;
    }
    const float inv = 1.f / s;
#pragma unroll 4
    for (int d = 0; d < 48; ++d) G[r * 48 + d] = L[d] * inv;
  }
  __syncthreads();
  if (tid < 192) {  // Weff row o = tid
    const int o = tid;
    f32x4 acc[12];
#pragma unroll
    for (int dv = 0; dv < 12; ++dv) acc[dv] = (f32x4){0.f, 0.f, 0.f, 0.f};
    for (int c = 0; c < 48; ++c) {
      const float w = wp[o * 49 + c];
      const f32x4* at = (const f32x4*)(G + c * 48);  // broadcast reads
#pragma unroll
      for (int dv = 0; dv < 12; ++dv) acc[dv] += w * at[dv];
    }
    u16* op = weff + ((size_t)b * 192 + o) * 192 + h * 48;
#pragma unroll
    for (int g8 = 0; g8 < 6; ++g8) {
      u16x8 ov;
#pragma unroll
      for (int j = 0; j < 8; ++j) {
        const int d = g8 * 8 + j;
        ov[j] = f2bf(acc[d >> 2][d & 3]);
      }
      *(u16x8*)(op + g8 * 8) = ov;
    }
  }
}

// ---------------------------------------------------------------------------
extern "C" void kernel_launch(void* const* d_in, const int* in_sizes, int n_in,
                              void* d_out, int out_size, void* d_ws,
                              size_t ws_size, hipStream_t stream) {
  (void)in_sizes; (void)n_in; (void)out_size; (void)ws_size;
  const float* x      = (const float*)d_in[0];  // [4][192][128][128]
  const float* w_qkv  = (const float*)d_in[1];  // [576][192]
  const float* w_dw   = (const float*)d_in[2];  // [576][9]
  const float* w_proj = (const float*)d_in[3];  // [192][192]
  const float* temp   = (const float*)d_in[4];  // [4]

  char* ws = (char*)d_ws;
  u16*   qkv     = (u16*)ws;                    // 75,497,472 B
  float* partial = (float*)(ws + 75497472);     //  4,718,592 B [16][2304][32]
  float* G       = (float*)(ws + 80216064);     //    147,456 B
  float* sq      = (float*)(ws + 80363520);     //      9,216 B
  u16*   Wq      = (u16*)(ws + 80372736);       //    221,184 B [576][192]
  u16*   Weff    = (u16*)(ws + 80593920);       //    294,912 B [4][192][192]

  // w_qkv -> bf16
  convert_w_kernel<<<dim3(432), 256, 0, stream>>>(w_qkv, Wq, 110592);
  // qkv[b][o][n] = sum_c x[c][n]*Wq[o][c]  (fused x-transpose; 3 j-groups)
  gemm_bt_kernel<true, true><<<dim3(128, 3, 4), 512, 0, stream>>>(
      x, Wq, qkv, (size_t)192 * 16384, 0, (size_t)576 * 16384, 16384);
  // depthwise 3x3 in-place + per-channel sum-of-squares
  dwconv_kernel<<<dim3(576, 4), 256, 0, stream>>>(qkv, w_dw, sq);
  // gram partials: 32 chunk-groups per (b,h), in-block wave reduction
  gram_kernel<<<dim3(32, 16), 256, 0, stream>>>(qkv, partial);
  // wide cross-chunk reduction
  reduce_partial_kernel<<<dim3(144), 256, 0, stream>>>(partial, G);
  // normalize + softmax + fold into projection
  softmax_weff_kernel<<<dim3(16), 256, 0, stream>>>(G, sq, temp, w_proj, Weff);
  // out[b][o][n] = sum_c2 v[c2][n]*Weff[o][c2] (fused v-transpose; 1 j-group)
  gemm_bt_kernel<false, false><<<dim3(128, 1, 4), 512, 0, stream>>>(
      qkv + (size_t)384 * 16384, Weff, d_out, (size_t)576 * 16384,
      (size_t)192 * 192, (size_t)192 * 16384, 16384);
}

// Round 10
// 135.643 us; speedup vs baseline: 1.1163x; 1.1163x over previous
//
#include <hip/hip_runtime.h>

typedef unsigned short u16;
typedef float f32x4 __attribute__((ext_vector_type(4)));
typedef __bf16 bf16x8 __attribute__((ext_vector_type(8)));
typedef unsigned short u16x8 __attribute__((ext_vector_type(8)));
typedef unsigned short u16x4 __attribute__((ext_vector_type(4)));

#define DEV static __device__ __forceinline__

DEV u16 f2bf(float f) {
  unsigned int u = __float_as_uint(f);
  u += 0x7FFFu + ((u >> 16) & 1u);   // round-to-nearest-even
  return (u16)(u >> 16);
}
DEV float bf2f(u16 h) { return __uint_as_float(((unsigned int)h) << 16); }

// async global->LDS, 16B per lane. LDS dest = wave-uniform base + lane*16.
DEV void gload_lds16(const void* g, void* l) {
  __builtin_amdgcn_global_load_lds(
      (__attribute__((address_space(1))) void*)(unsigned long long)g,
      (__attribute__((address_space(3))) void*)l, 16, 0, 0);
}

// counted vmcnt wait; n is compile-time constant after full unroll
DEV void vm_wait(int n) {
  switch (n) {
    case 0:  asm volatile("s_waitcnt vmcnt(0)" ::: "memory"); break;
    case 4:  asm volatile("s_waitcnt vmcnt(4)" ::: "memory"); break;
    case 6:  asm volatile("s_waitcnt vmcnt(6)" ::: "memory"); break;
    case 8:  asm volatile("s_waitcnt vmcnt(8)" ::: "memory"); break;
    case 10: asm volatile("s_waitcnt vmcnt(10)" ::: "memory"); break;
    default: asm volatile("s_waitcnt vmcnt(14)" ::: "memory"); break;
  }
}

// ---------------------------------------------------------------------------
// K0b: convert w_qkv fp32 -> bf16 (plain row-major [576][192])
__global__ __launch_bounds__(256) void convert_w_kernel(
    const float* __restrict__ in, u16* __restrict__ out, int n) {
  int i = blockIdx.x * 256 + threadIdx.x;
  if (i < n) out[i] = f2bf(in[i]);
}

// ---------------------------------------------------------------------------
// B^T GEMM, WAVE-AUTONOMOUS j-loop. C[j][m] = sum_k A^T[m][k]*B[j][k], K=192.
// BM=64 px, 4 waves. sA (24 KB, fused transpose+convert, swizzled) is staged
// once behind the ONLY barrier. Each wave then owns a private 2x6 KB B
// double-buffer: per 16-row B-tile {counted vm_wait -> 6 ds_read_b128 ->
// 24 MFMA -> 4 stores -> prefetch tile t+2 into the drained buffer}.
// gload_lds completion is wave-local (vmcnt), so NO barriers / block-wide
// drains in the loop — waves free-run like independent blocks (dwconv
// recipe). LDS 72 KB -> 2 blocks/CU = 8 independent waves/CU.
// grid = (256 m-tiles, 4 batches); wave w covers B rows [w*NJT*16, +NJT*16).
template <bool IN_F32, bool OUT_BF16, int NJT>
__global__ __launch_bounds__(256, 2) void gemm_bt_kernel(
    const void* __restrict__ Av, const u16* __restrict__ B,
    void* __restrict__ Cv, size_t aBatch, size_t bBatch, size_t cBatch,
    int ldC) {
  __shared__ __align__(16) char smem[73728];
  char* sA = smem;  // [64][384B] content-swizzled

  const int tid = threadIdx.x, wave = tid >> 6, lane = tid & 63;
  const int m0 = blockIdx.x * 64, b = blockIdx.y;
  const char* Bbase = (const char*)(B + (size_t)b * bBatch);
  char* bufs = smem + 24576 + wave * 12288;  // wave-private 2 x 6144 B
  const int jwbase = wave * (NJT * 16);

  // ---- A: issue global loads first (B-stage gloads go behind them)
  f32x4 vaf[3][4];
  u16x8 vau[2][4];
  if (IN_F32) {
    const float* Xb = (const float*)Av + (size_t)b * aBatch + m0;
    const int cbl = tid & 15, iq = tid >> 4;
#pragma unroll
    for (int p = 0; p < 3; ++p)
#pragma unroll
      for (int r = 0; r < 4; ++r)
        vaf[p][r] = *(const f32x4*)(Xb + (size_t)((p * 16 + cbl) * 4 + r) *
                                             16384 + iq * 4);
  } else {
    const u16* Vb = (const u16*)Av + (size_t)b * aBatch + m0;
#pragma unroll
    for (int p = 0; p < 2; ++p) {
      const int task = p * 256 + tid;  // 48 c-quads x 8 n-octs = 384 tasks
      if (task < 384) {
        const int cb = task >> 3, io = task & 7;
#pragma unroll
        for (int r = 0; r < 4; ++r)
          vau[p][r] = *(const u16x8*)(Vb + (size_t)(cb * 4 + r) * 16384 +
                                      io * 8);
      }
    }
  }
  // ---- stage wave-private B tiles 0 and 1
#pragma unroll
  for (int t = 0; t < 2; ++t) {
    if (t < NJT) {
#pragma unroll
      for (int i = 0; i < 6; ++i) {
        const int d = i * 1024 + lane * 16;
        const int row = d / 384, inrow = d - row * 384;
        gload_lds16(Bbase + (size_t)(jwbase + t * 16 + row) * 384 +
                        (inrow ^ ((row & 7) << 4)),
                    bufs + t * 6144 + i * 1024);
      }
    }
  }
  // ---- A: transpose + convert + swizzled ds_write
  if (IN_F32) {
    const int cbl = tid & 15, iq = tid >> 4;
#pragma unroll
    for (int p = 0; p < 3; ++p) {
      const int cb = p * 16 + cbl;
#pragma unroll
      for (int j = 0; j < 4; ++j) {
        const int n = iq * 4 + j;
        u16x4 col;
        col[0] = f2bf(vaf[p][0][j]);
        col[1] = f2bf(vaf[p][1][j]);
        col[2] = f2bf(vaf[p][2][j]);
        col[3] = f2bf(vaf[p][3][j]);
        *(u16x4*)(sA + n * 384 + ((cb * 8) ^ ((n & 7) << 4))) = col;
      }
    }
  } else {
#pragma unroll
    for (int p = 0; p < 2; ++p) {
      const int task = p * 256 + tid;
      if (task < 384) {
        const int cb = task >> 3, io = task & 7;
#pragma unroll
        for (int j = 0; j < 8; ++j) {
          const int n = io * 8 + j;
          u16x4 col;
          col[0] = vau[p][0][j];
          col[1] = vau[p][1][j];
          col[2] = vau[p][2][j];
          col[3] = vau[p][3][j];
          *(u16x4*)(sA + n * 384 + ((cb * 8) ^ ((n & 7) << 4))) = col;
        }
      }
    }
  }
  asm volatile("s_waitcnt lgkmcnt(0)" ::: "memory");
  __builtin_amdgcn_s_barrier();  // the only barrier (sA is shared)

  const int l15 = lane & 15, lg = lane >> 4;
  const int swm = (l15 & 7) << 4;

  // ---- A fragments hoisted (full 64 px x 192 ch per wave)
  bf16x8 af[4][6];
#pragma unroll
  for (int mi = 0; mi < 4; ++mi)
#pragma unroll
    for (int ks = 0; ks < 6; ++ks)
      af[mi][ks] = *(const bf16x8*)(sA + (mi * 16 + l15) * 384 +
                                    ((ks * 64 + lg * 16) ^ swm));

  // ---- wave-private tile loop: no barriers, counted wave-local vmcnt
#pragma unroll
  for (int t = 0; t < NJT; ++t) {
    // ensure stage(t) done; leave stage(t+1) [6] + store(t-1) [4] in flight
    vm_wait(t == 0 ? (NJT > 1 ? 6 : 0) : (4 + (t + 1 < NJT ? 6 : 0)));
    __builtin_amdgcn_sched_barrier(0);
    char* bw = bufs + (t & 1) * 6144;
    bf16x8 bfv[6];
#pragma unroll
    for (int ks = 0; ks < 6; ++ks)
      bfv[ks] = *(const bf16x8*)(bw + l15 * 384 + ((ks * 64 + lg * 16) ^ swm));
    f32x4 acc[4];
#pragma unroll
    for (int mi = 0; mi < 4; ++mi) acc[mi] = (f32x4){0.f, 0.f, 0.f, 0.f};
#pragma unroll
    for (int ks = 0; ks < 6; ++ks)
#pragma unroll
      for (int mi = 0; mi < 4; ++mi)
        acc[mi] = __builtin_amdgcn_mfma_f32_16x16x32_bf16(af[mi][ks], bfv[ks],
                                                          acc[mi], 0, 0, 0);
    // store tile t (4 vmcnt entries, ride in flight ~2 tiles)
    const int jrow = jwbase + t * 16 + l15;
    if (OUT_BF16) {
      u16* Cb = (u16*)Cv + (size_t)b * cBatch;
#pragma unroll
      for (int mi = 0; mi < 4; ++mi) {
        u16x4 ov;
#pragma unroll
        for (int r = 0; r < 4; ++r) ov[r] = f2bf(acc[mi][r]);
        *(u16x4*)(Cb + (size_t)jrow * ldC + m0 + mi * 16 + lg * 4) = ov;
      }
    } else {
      float* Cb = (float*)Cv + (size_t)b * cBatch;
#pragma unroll
      for (int mi = 0; mi < 4; ++mi)
        *(f32x4*)(Cb + (size_t)jrow * ldC + m0 + mi * 16 + lg * 4) = acc[mi];
    }
    // prefetch tile t+2 into the buffer drained this iteration (MFMA's
    // lgkm waits already ordered all bfv ds_reads before this point)
    if (t + 2 < NJT) {
      __builtin_amdgcn_sched_barrier(0);
#pragma unroll
      for (int i = 0; i < 6; ++i) {
        const int d = i * 1024 + lane * 16;
        const int row = d / 384, inrow = d - row * 384;
        gload_lds16(Bbase + (size_t)(jwbase + (t + 2) * 16 + row) * 384 +
                        (inrow ^ ((row & 7) << 4)),
                    bw + i * 1024);
      }
    }
  }
}

// ---------------------------------------------------------------------------
// Depthwise 3x3 (pad 1), in-place on bf16 [b][576][128][128]; per-channel
// sum-of-squares for the q/k L2 norms. One block per (b, channel).
__global__ __launch_bounds__(256) void dwconv_kernel(
    u16* __restrict__ qkv, const float* __restrict__ wdw,
    float* __restrict__ sq) {
  __shared__ u16 img[16384];  // full 128x128 channel, 32 KB
  __shared__ float red[4];
  const int o = blockIdx.x, b = blockIdx.y;
  const size_t base = ((size_t)b * 576 + o) * 16384;
  const int tid = threadIdx.x, wave = tid >> 6, lane = tid & 63;
#pragma unroll
  for (int i = 0; i < 8; ++i) {
    const int off = (i * 4 + wave) * 1024;
    gload_lds16((const char*)qkv + base * 2 + off + lane * 16, (char*)img + off);
  }
  asm volatile("s_waitcnt vmcnt(0)" ::: "memory");
  __syncthreads();
  float w[9];
#pragma unroll
  for (int j = 0; j < 9; ++j) w[j] = wdw[o * 9 + j];
  float sqacc = 0.f;
  for (int it = 0; it < 8; ++it) {
    const int chunk = it * 256 + tid;  // 2048 chunks of 8 px
    const int px0 = chunk * 8;
    const int y = px0 >> 7, x0 = px0 & 127;
    float acc[8];
#pragma unroll
    for (int j = 0; j < 8; ++j) acc[j] = 0.f;
#pragma unroll
    for (int dy = -1; dy <= 1; ++dy) {
      const int yy = y + dy;
      float v[10];
      if (yy >= 0 && yy <= 127) {
        const u16* rowp = img + yy * 128 + x0;
        u16x8 m = *(const u16x8*)rowp;
#pragma unroll
        for (int j = 0; j < 8; ++j) v[j + 1] = bf2f(m[j]);
        v[0] = (x0 > 0) ? bf2f(rowp[-1]) : 0.f;
        v[9] = (x0 < 120) ? bf2f(rowp[8]) : 0.f;
      } else {
#pragma unroll
        for (int j = 0; j < 10; ++j) v[j] = 0.f;
      }
      const float w0 = w[(dy + 1) * 3], w1 = w[(dy + 1) * 3 + 1],
                  w2 = w[(dy + 1) * 3 + 2];
#pragma unroll
      for (int j = 0; j < 8; ++j) acc[j] += w0 * v[j] + w1 * v[j + 1] + w2 * v[j + 2];
    }
    u16x8 ov;
#pragma unroll
    for (int j = 0; j < 8; ++j) {
      sqacc += acc[j] * acc[j];
      ov[j] = f2bf(acc[j]);
    }
    *(u16x8*)(qkv + base + px0) = ov;  // in-place: all reads came from LDS
  }
#pragma unroll
  for (int s = 32; s > 0; s >>= 1) sqacc += __shfl_xor(sqacc, s, 64);
  if (lane == 0) red[wave] = sqacc;
  __syncthreads();
  if (tid == 0) sq[b * 576 + o] = red[0] + red[1] + red[2] + red[3];
}

// ---------------------------------------------------------------------------
// Gram: G_partial[c][d] = sum_n q[c][n]*k[d][n] over a 512-n block (4 waves x
// 128 n each, reduced in-block through LDS). Tile content XOR-swizzled.
// grid (32 chunk-groups, 16 bh); partial[bh][pos][chunk32].
__global__ __launch_bounds__(256) void gram_kernel(
    const u16* __restrict__ qkv, float* __restrict__ partial) {
  __shared__ u16 tiles[4 * 3072];   // per-wave [96][32] bf16 (q 0-47, k 48-95)
  __shared__ float red[4 * 2304];   // per-wave gram copies for in-block reduce
  const int bh = blockIdx.y, b = bh >> 2, h = bh & 3;
  const int g = blockIdx.x;                  // chunk 0..31
  const int wave = threadIdx.x >> 6, lane = threadIdx.x & 63;
  const int n0 = g * 512 + wave * 128;
  const u16* qb = qkv + ((size_t)b * 576 + h * 48) * 16384;
  const u16* kb = qb + (size_t)192 * 16384;
  char* tl = (char*)(tiles + wave * 3072);
  const int l15 = lane & 15, lg = lane >> 4;
  const int swz = (l15 & 3) << 4;
  f32x4 acc[3][3];
#pragma unroll
  for (int i = 0; i < 3; ++i)
#pragma unroll
    for (int j = 0; j < 3; ++j) acc[i][j] = (f32x4){0.f, 0.f, 0.f, 0.f};

  for (int ks = 0; ks < 4; ++ks) {
    const int nn = n0 + ks * 32;
    asm volatile("s_waitcnt lgkmcnt(0)" ::: "memory");
#pragma unroll
    for (int i = 0; i < 6; ++i) {
      const int flat = i * 1024 + lane * 16;
      const int row = flat >> 6, colb = flat & 63;
      const u16* src = (row < 48) ? (qb + (size_t)row * 16384 + nn)
                                  : (kb + (size_t)(row - 48) * 16384 + nn);
      gload_lds16((const char*)src + (colb ^ ((row & 3) << 4)), tl + i * 1024);
    }
    asm volatile("s_waitcnt vmcnt(0)" ::: "memory");
    bf16x8 qf[3], kf[3];
#pragma unroll
    for (int f = 0; f < 3; ++f) {
      qf[f] = *(const bf16x8*)(tl + (f * 16 + l15) * 64 + ((lg * 16) ^ swz));
      kf[f] = *(const bf16x8*)(tl + (48 + f * 16 + l15) * 64 + ((lg * 16) ^ swz));
    }
#pragma unroll
    for (int i = 0; i < 3; ++i)
#pragma unroll
      for (int j = 0; j < 3; ++j)
        acc[i][j] = __builtin_amdgcn_mfma_f32_16x16x32_bf16(qf[i], kf[j],
                                                            acc[i][j], 0, 0, 0);
  }
  // in-block reduce over the 4 waves
  {
    float* rw = red + wave * 2304;
#pragma unroll
    for (int i = 0; i < 3; ++i)
#pragma unroll
      for (int j = 0; j < 3; ++j)
#pragma unroll
        for (int r = 0; r < 4; ++r)
          rw[(i * 16 + lg * 4 + r) * 48 + (j * 16 + l15)] = acc[i][j][r];
  }
  __syncthreads();
#pragma unroll
  for (int it = 0; it < 9; ++it) {
    const int p = it * 256 + threadIdx.x;
    const float s = red[p] + red[2304 + p] + red[4608 + p] + red[6912 + p];
    partial[((size_t)bh * 2304 + p) * 32 + g] = s;
  }
}

// ---------------------------------------------------------------------------
// Wide reduction of gram partials: G[bh*2304+p] = sum over 32 chunks.
__global__ __launch_bounds__(256) void reduce_partial_kernel(
    const float* __restrict__ partial, float* __restrict__ G) {
  const int idx = blockIdx.x * 256 + threadIdx.x;  // 0..36863
  const f32x4* pp = (const f32x4*)(partial + (size_t)idx * 32);
  const f32x4 a = (pp[0] + pp[1]) + (pp[2] + pp[3]) +
                  (pp[4] + pp[5]) + (pp[6] + pp[7]);
  G[idx] = a.x + a.y + a.z + a.w;
}

// ---------------------------------------------------------------------------
// Normalize, softmax, fold attn into projection (plain row-major Weff out).
__global__ __launch_bounds__(256) void softmax_weff_kernel(
    const float* __restrict__ Gin, const float* __restrict__ sq,
    const float* __restrict__ temp, const float* __restrict__ wproj,
    u16* __restrict__ weff) {
  __shared__ float G[2304];        // gram -> attn (in place)
  __shared__ float wp[192 * 49];   // wproj slice, pad 49 (odd bank stride)
  __shared__ float nq[48], nk[48];
  const int bh = blockIdx.x, b = bh >> 2, h = bh & 3;
  const int tid = threadIdx.x;
#pragma unroll
  for (int it = 0; it < 36; ++it) {  // load wproj [192][h*48 .. h*48+48)
    const int j = it * 256 + tid;
    const int o = j / 48, c = j - o * 48;
    wp[o * 49 + c] = wproj[o * 192 + h * 48 + c];
  }
#pragma unroll
  for (int it = 0; it < 9; ++it) {
    const int p = it * 256 + tid;
    G[p] = Gin[(size_t)bh * 2304 + p];
  }
  if (tid < 48) {
    nq[tid] = fmaxf(sqrtf(sq[b * 576 + h * 48 + tid]), 1e-12f);
    nk[tid] = fmaxf(sqrtf(sq[b * 576 + 192 + h * 48 + tid]), 1e-12f);
  }
  __syncthreads();
  if (tid < 48) {  // row softmax (48 rows)
    const int r = tid;
    const float inq = temp[h] / nq[r];
    float L[48];
    float mx = -3.4e38f;
#pragma unroll 4
    for (int d = 0; d < 48; ++d) {
      const float v = G[r * 48 + d] * inq / nk[d];
      L[d] = v;
      mx = fmaxf(mx, v);
    }
    float s = 0.f;
#pragma unroll 4
    for (int d = 0; d < 48; ++d) {
      const float e = __expf(L[d] - mx);
      L[d] = e;
      s += e;
    }
    const float inv = 1.f / s;
#pragma unroll 4
    for (int d = 0; d < 48; ++d) G[r * 48 + d] = L[d] * inv;
  }
  __syncthreads();
  if (tid < 192) {  // Weff row o = tid
    const int o = tid;
    f32x4 acc[12];
#pragma unroll
    for (int dv = 0; dv < 12; ++dv) acc[dv] = (f32x4){0.f, 0.f, 0.f, 0.f};
    for (int c = 0; c < 48; ++c) {
      const float w = wp[o * 49 + c];
      const f32x4* at = (const f32x4*)(G + c * 48);  // broadcast reads
#pragma unroll
      for (int dv = 0; dv < 12; ++dv) acc[dv] += w * at[dv];
    }
    u16* op = weff + ((size_t)b * 192 + o) * 192 + h * 48;
#pragma unroll
    for (int g8 = 0; g8 < 6; ++g8) {
      u16x8 ov;
#pragma unroll
      for (int j = 0; j < 8; ++j) {
        const int d = g8 * 8 + j;
        ov[j] = f2bf(acc[d >> 2][d & 3]);
      }
      *(u16x8*)(op + g8 * 8) = ov;
    }
  }
}

// ---------------------------------------------------------------------------
extern "C" void kernel_launch(void* const* d_in, const int* in_sizes, int n_in,
                              void* d_out, int out_size, void* d_ws,
                              size_t ws_size, hipStream_t stream) {
  (void)in_sizes; (void)n_in; (void)out_size; (void)ws_size;
  const float* x      = (const float*)d_in[0];  // [4][192][128][128]
  const float* w_qkv  = (const float*)d_in[1];  // [576][192]
  const float* w_dw   = (const float*)d_in[2];  // [576][9]
  const float* w_proj = (const float*)d_in[3];  // [192][192]
  const float* temp   = (const float*)d_in[4];  // [4]

  char* ws = (char*)d_ws;
  u16*   qkv     = (u16*)ws;                    // 75,497,472 B
  float* partial = (float*)(ws + 75497472);     //  4,718,592 B [16][2304][32]
  float* G       = (float*)(ws + 80216064);     //    147,456 B
  float* sq      = (float*)(ws + 80363520);     //      9,216 B
  u16*   Wq      = (u16*)(ws + 80372736);       //    221,184 B [576][192]
  u16*   Weff    = (u16*)(ws + 80593920);       //    294,912 B [4][192][192]

  // w_qkv -> bf16
  convert_w_kernel<<<dim3(432), 256, 0, stream>>>(w_qkv, Wq, 110592);
  // qkv[b][o][n] = sum_c x[c][n]*Wq[o][c]  (fused x-transpose; 9 tiles/wave)
  gemm_bt_kernel<true, true, 9><<<dim3(256, 4), 256, 0, stream>>>(
      x, Wq, qkv, (size_t)192 * 16384, 0, (size_t)576 * 16384, 16384);
  // depthwise 3x3 in-place + per-channel sum-of-squares
  dwconv_kernel<<<dim3(576, 4), 256, 0, stream>>>(qkv, w_dw, sq);
  // gram partials: 32 chunk-groups per (b,h), in-block wave reduction
  gram_kernel<<<dim3(32, 16), 256, 0, stream>>>(qkv, partial);
  // wide cross-chunk reduction
  reduce_partial_kernel<<<dim3(144), 256, 0, stream>>>(partial, G);
  // normalize + softmax + fold into projection
  softmax_weff_kernel<<<dim3(16), 256, 0, stream>>>(G, sq, temp, w_proj, Weff);
  // out[b][o][n] = sum_c2 v[c2][n]*Weff[o][c2] (fused v-transpose; 3/wave)
  gemm_bt_kernel<false, false, 3><<<dim3(256, 4), 256, 0, stream>>>(
      qkv + (size_t)384 * 16384, Weff, d_out, (size_t)576 * 16384,
      (size_t)192 * 192, (size_t)192 * 16384, 16384);
}

// Round 11
// 135.227 us; speedup vs baseline: 1.1197x; 1.0031x over previous
//
#include <hip/hip_runtime.h>

typedef unsigned short u16;
typedef float f32x4 __attribute__((ext_vector_type(4)));
typedef __bf16 bf16x8 __attribute__((ext_vector_type(8)));
typedef unsigned short u16x8 __attribute__((ext_vector_type(8)));
typedef unsigned short u16x4 __attribute__((ext_vector_type(4)));

#define DEV static __device__ __forceinline__

// padded row stride for the qkv intermediate (breaks 32KB pow-2 channel camping)
#define QS 16448

DEV u16 f2bf(float f) {
  unsigned int u = __float_as_uint(f);
  u += 0x7FFFu + ((u >> 16) & 1u);   // round-to-nearest-even
  return (u16)(u >> 16);
}
DEV float bf2f(u16 h) { return __uint_as_float(((unsigned int)h) << 16); }

// async global->LDS, 16B per lane. LDS dest = wave-uniform base + lane*16.
DEV void gload_lds16(const void* g, void* l) {
  __builtin_amdgcn_global_load_lds(
      (__attribute__((address_space(1))) void*)(unsigned long long)g,
      (__attribute__((address_space(3))) void*)l, 16, 0, 0);
}

// counted vmcnt wait; n is compile-time constant after full unroll
DEV void vm_wait(int n) {
  switch (n) {
    case 0:  asm volatile("s_waitcnt vmcnt(0)" ::: "memory"); break;
    case 2:  asm volatile("s_waitcnt vmcnt(2)" ::: "memory"); break;
    case 4:  asm volatile("s_waitcnt vmcnt(4)" ::: "memory"); break;
    case 6:  asm volatile("s_waitcnt vmcnt(6)" ::: "memory"); break;
    case 8:  asm volatile("s_waitcnt vmcnt(8)" ::: "memory"); break;
    case 10: asm volatile("s_waitcnt vmcnt(10)" ::: "memory"); break;
    default: asm volatile("s_waitcnt vmcnt(14)" ::: "memory"); break;
  }
}

// ---------------------------------------------------------------------------
// K0b: convert w_qkv fp32 -> bf16 (plain row-major [576][192])
__global__ __launch_bounds__(256) void convert_w_kernel(
    const float* __restrict__ in, u16* __restrict__ out, int n) {
  int i = blockIdx.x * 256 + threadIdx.x;
  if (i < n) out[i] = f2bf(in[i]);
}

// ---------------------------------------------------------------------------
// B^T GEMM, wave-autonomous j-loop (R9 schedule) + LDS-restaged coalesced
// epilogue. C[j][m] = sum_k A^T[m][k]*B[j][k], K=192. BM=64 px, 4 waves.
// sA (24 KB, fused transpose+convert, swizzled) staged once; after the A
// fragments are hoisted to registers, sA is DEAD and is reused as per-wave
// restage buffers for the C-tiles, so stores are issued as large contiguous
// segments (8x128 B for bf16 / 4x256 B for f32 per instruction) instead of
// 16x32 B scatter. Wave-private B double-buffer, counted wave-local vmcnt,
// no block-wide sync in the loop. LDS 72 KB -> 2 blocks/CU.
template <bool IN_F32, bool OUT_BF16, int NJT>
__global__ __launch_bounds__(256, 2) void gemm_bt_kernel(
    const void* __restrict__ Av, const u16* __restrict__ B,
    void* __restrict__ Cv, size_t aBatch, int aStride, size_t bBatch,
    size_t cBatch, int ldC) {
  __shared__ __align__(16) char smem[73728];
  char* sA = smem;  // [64][384B] content-swizzled; later: restage buffers

  const int tid = threadIdx.x, wave = tid >> 6, lane = tid & 63;
  const int m0 = blockIdx.x * 64, b = blockIdx.y;
  const char* Bbase = (const char*)(B + (size_t)b * bBatch);
  char* bufs = smem + 24576 + wave * 12288;  // wave-private 2 x 6144 B
  const int jwbase = wave * (NJT * 16);
  constexpr int S = OUT_BF16 ? 2 : 4;  // store instrs per tile (epilogue)

  // ---- A: issue global loads first (B-stage gloads go behind them)
  f32x4 vaf[3][4];
  u16x8 vau[2][4];
  if (IN_F32) {
    const float* Xb = (const float*)Av + (size_t)b * aBatch + m0;
    const int cbl = tid & 15, iq = tid >> 4;
#pragma unroll
    for (int p = 0; p < 3; ++p)
#pragma unroll
      for (int r = 0; r < 4; ++r)
        vaf[p][r] = *(const f32x4*)(Xb + (size_t)((p * 16 + cbl) * 4 + r) *
                                             aStride + iq * 4);
  } else {
    const u16* Vb = (const u16*)Av + (size_t)b * aBatch + m0;
#pragma unroll
    for (int p = 0; p < 2; ++p) {
      const int task = p * 256 + tid;  // 48 c-quads x 8 n-octs = 384 tasks
      if (task < 384) {
        const int cb = task >> 3, io = task & 7;
#pragma unroll
        for (int r = 0; r < 4; ++r)
          vau[p][r] = *(const u16x8*)(Vb + (size_t)(cb * 4 + r) * aStride +
                                      io * 8);
      }
    }
  }
  // ---- stage wave-private B tiles 0 and 1
#pragma unroll
  for (int t = 0; t < 2; ++t) {
    if (t < NJT) {
#pragma unroll
      for (int i = 0; i < 6; ++i) {
        const int d = i * 1024 + lane * 16;
        const int row = d / 384, inrow = d - row * 384;
        gload_lds16(Bbase + (size_t)(jwbase + t * 16 + row) * 384 +
                        (inrow ^ ((row & 7) << 4)),
                    bufs + t * 6144 + i * 1024);
      }
    }
  }
  // ---- A: transpose + convert + swizzled ds_write
  if (IN_F32) {
    const int cbl = tid & 15, iq = tid >> 4;
#pragma unroll
    for (int p = 0; p < 3; ++p) {
      const int cb = p * 16 + cbl;
#pragma unroll
      for (int j = 0; j < 4; ++j) {
        const int n = iq * 4 + j;
        u16x4 col;
        col[0] = f2bf(vaf[p][0][j]);
        col[1] = f2bf(vaf[p][1][j]);
        col[2] = f2bf(vaf[p][2][j]);
        col[3] = f2bf(vaf[p][3][j]);
        *(u16x4*)(sA + n * 384 + ((cb * 8) ^ ((n & 7) << 4))) = col;
      }
    }
  } else {
#pragma unroll
    for (int p = 0; p < 2; ++p) {
      const int task = p * 256 + tid;
      if (task < 384) {
        const int cb = task >> 3, io = task & 7;
#pragma unroll
        for (int j = 0; j < 8; ++j) {
          const int n = io * 8 + j;
          u16x4 col;
          col[0] = vau[p][0][j];
          col[1] = vau[p][1][j];
          col[2] = vau[p][2][j];
          col[3] = vau[p][3][j];
          *(u16x4*)(sA + n * 384 + ((cb * 8) ^ ((n & 7) << 4))) = col;
        }
      }
    }
  }
  asm volatile("s_waitcnt lgkmcnt(0)" ::: "memory");
  __builtin_amdgcn_s_barrier();  // sA staged (all waves)

  const int l15 = lane & 15, lg = lane >> 4;
  const int swm = (l15 & 7) << 4;

  // ---- A fragments hoisted (full 64 px x 192 ch per wave); sA dead after
  bf16x8 af[4][6];
#pragma unroll
  for (int mi = 0; mi < 4; ++mi)
#pragma unroll
    for (int ks = 0; ks < 6; ++ks)
      af[mi][ks] = *(const bf16x8*)(sA + (mi * 16 + l15) * 384 +
                                    ((ks * 64 + lg * 16) ^ swm));
  asm volatile("s_waitcnt lgkmcnt(0)" ::: "memory");
  __builtin_amdgcn_s_barrier();  // all waves done reading sA -> reusable

  char* rbuf = sA + wave * 6144;  // wave-private restage buffer

  // ---- wave-private tile loop: no barriers, counted wave-local vmcnt
#pragma unroll
  for (int t = 0; t < NJT; ++t) {
    // stage(t) must be done; stores(t-1) [S] + stage(t+1) [6] stay in flight
    vm_wait(t == 0 ? (NJT > 1 ? 6 : 0) : (S + (t + 1 < NJT ? 6 : 0)));
    __builtin_amdgcn_sched_barrier(0);
    char* bw = bufs + (t & 1) * 6144;
    bf16x8 bfv[6];
#pragma unroll
    for (int ks = 0; ks < 6; ++ks)
      bfv[ks] = *(const bf16x8*)(bw + l15 * 384 + ((ks * 64 + lg * 16) ^ swm));
    f32x4 acc[4];
#pragma unroll
    for (int mi = 0; mi < 4; ++mi) acc[mi] = (f32x4){0.f, 0.f, 0.f, 0.f};
#pragma unroll
    for (int ks = 0; ks < 6; ++ks)
#pragma unroll
      for (int mi = 0; mi < 4; ++mi)
        acc[mi] = __builtin_amdgcn_mfma_f32_16x16x32_bf16(af[mi][ks], bfv[ks],
                                                          acc[mi], 0, 0, 0);
    // ---- restaged, coalesced store of tile t
    if (OUT_BF16) {
      // pack to bf16 in LDS [16 rows][136 B] (odd dword stride -> no conflict)
#pragma unroll
      for (int mi = 0; mi < 4; ++mi) {
        u16x4 ov;
#pragma unroll
        for (int r = 0; r < 4; ++r) ov[r] = f2bf(acc[mi][r]);
        *(u16x4*)(rbuf + l15 * 136 + mi * 32 + lg * 8) = ov;
      }
      asm volatile("s_waitcnt lgkmcnt(0)" ::: "memory");
      u16* Cb = (u16*)Cv + (size_t)b * cBatch;
#pragma unroll
      for (int half = 0; half < 2; ++half) {  // 2 instrs x 8 rows x 128 B
        const int row = half * 8 + (lane >> 3);
        const u16x8 val = *(const u16x8*)(rbuf + row * 136 + (lane & 7) * 16);
        *(u16x8*)(Cb + (size_t)(jwbase + t * 16 + row) * ldC + m0 +
                  (lane & 7) * 8) = val;
      }
    } else {
      // f32 restage [16 rows][272 B]
#pragma unroll
      for (int mi = 0; mi < 4; ++mi)
        *(f32x4*)(rbuf + l15 * 272 + mi * 64 + lg * 16) = acc[mi];
      asm volatile("s_waitcnt lgkmcnt(0)" ::: "memory");
      float* Cb = (float*)Cv + (size_t)b * cBatch;
#pragma unroll
      for (int q = 0; q < 4; ++q) {  // 4 instrs x 4 rows x 256 B
        const int row = q * 4 + (lane >> 4);
        const f32x4 val = *(const f32x4*)(rbuf + row * 272 + (lane & 15) * 16);
        *(f32x4*)(Cb + (size_t)(jwbase + t * 16 + row) * ldC + m0 +
                  (lane & 15) * 4) = val;
      }
    }
    // prefetch tile t+2 into the buffer drained this iteration
    if (t + 2 < NJT) {
      __builtin_amdgcn_sched_barrier(0);
#pragma unroll
      for (int i = 0; i < 6; ++i) {
        const int d = i * 1024 + lane * 16;
        const int row = d / 384, inrow = d - row * 384;
        gload_lds16(Bbase + (size_t)(jwbase + (t + 2) * 16 + row) * 384 +
                        (inrow ^ ((row & 7) << 4)),
                    bw + i * 1024);
      }
    }
  }
}

// ---------------------------------------------------------------------------
// Depthwise 3x3 (pad 1), in-place on bf16 [b][576][QS-strided 128x128];
// per-channel sum-of-squares. One block per (b, channel).
__global__ __launch_bounds__(256) void dwconv_kernel(
    u16* __restrict__ qkv, const float* __restrict__ wdw,
    float* __restrict__ sq) {
  __shared__ u16 img[16384];  // full 128x128 channel, 32 KB
  __shared__ float red[4];
  const int o = blockIdx.x, b = blockIdx.y;
  const size_t base = ((size_t)b * 576 + o) * QS;
  const int tid = threadIdx.x, wave = tid >> 6, lane = tid & 63;
#pragma unroll
  for (int i = 0; i < 8; ++i) {
    const int off = (i * 4 + wave) * 1024;
    gload_lds16((const char*)qkv + base * 2 + off + lane * 16, (char*)img + off);
  }
  asm volatile("s_waitcnt vmcnt(0)" ::: "memory");
  __syncthreads();
  float w[9];
#pragma unroll
  for (int j = 0; j < 9; ++j) w[j] = wdw[o * 9 + j];
  float sqacc = 0.f;
  for (int it = 0; it < 8; ++it) {
    const int chunk = it * 256 + tid;  // 2048 chunks of 8 px
    const int px0 = chunk * 8;
    const int y = px0 >> 7, x0 = px0 & 127;
    float acc[8];
#pragma unroll
    for (int j = 0; j < 8; ++j) acc[j] = 0.f;
#pragma unroll
    for (int dy = -1; dy <= 1; ++dy) {
      const int yy = y + dy;
      float v[10];
      if (yy >= 0 && yy <= 127) {
        const u16* rowp = img + yy * 128 + x0;
        u16x8 m = *(const u16x8*)rowp;
#pragma unroll
        for (int j = 0; j < 8; ++j) v[j + 1] = bf2f(m[j]);
        v[0] = (x0 > 0) ? bf2f(rowp[-1]) : 0.f;
        v[9] = (x0 < 120) ? bf2f(rowp[8]) : 0.f;
      } else {
#pragma unroll
        for (int j = 0; j < 10; ++j) v[j] = 0.f;
      }
      const float w0 = w[(dy + 1) * 3], w1 = w[(dy + 1) * 3 + 1],
                  w2 = w[(dy + 1) * 3 + 2];
#pragma unroll
      for (int j = 0; j < 8; ++j) acc[j] += w0 * v[j] + w1 * v[j + 1] + w2 * v[j + 2];
    }
    u16x8 ov;
#pragma unroll
    for (int j = 0; j < 8; ++j) {
      sqacc += acc[j] * acc[j];
      ov[j] = f2bf(acc[j]);
    }
    *(u16x8*)(qkv + base + px0) = ov;  // in-place: all reads came from LDS
  }
#pragma unroll
  for (int s = 32; s > 0; s >>= 1) sqacc += __shfl_xor(sqacc, s, 64);
  if (lane == 0) red[wave] = sqacc;
  __syncthreads();
  if (tid == 0) sq[b * 576 + o] = red[0] + red[1] + red[2] + red[3];
}

// ---------------------------------------------------------------------------
// Gram: G_partial[c][d] = sum_n q[c][n]*k[d][n] over a 512-n block (4 waves x
// 128 n each, reduced in-block through LDS). Tile content XOR-swizzled.
// grid (32 chunk-groups, 16 bh); partial[bh][pos][chunk32].
__global__ __launch_bounds__(256) void gram_kernel(
    const u16* __restrict__ qkv, float* __restrict__ partial) {
  __shared__ u16 tiles[4 * 3072];   // per-wave [96][32] bf16 (q 0-47, k 48-95)
  __shared__ float red[4 * 2304];   // per-wave gram copies for in-block reduce
  const int bh = blockIdx.y, b = bh >> 2, h = bh & 3;
  const int g = blockIdx.x;                  // chunk 0..31
  const int wave = threadIdx.x >> 6, lane = threadIdx.x & 63;
  const int n0 = g * 512 + wave * 128;
  const u16* qb = qkv + ((size_t)b * 576 + h * 48) * QS;
  const u16* kb = qb + (size_t)192 * QS;
  char* tl = (char*)(tiles + wave * 3072);
  const int l15 = lane & 15, lg = lane >> 4;
  const int swz = (l15 & 3) << 4;
  f32x4 acc[3][3];
#pragma unroll
  for (int i = 0; i < 3; ++i)
#pragma unroll
    for (int j = 0; j < 3; ++j) acc[i][j] = (f32x4){0.f, 0.f, 0.f, 0.f};

  for (int ks = 0; ks < 4; ++ks) {
    const int nn = n0 + ks * 32;
    asm volatile("s_waitcnt lgkmcnt(0)" ::: "memory");
#pragma unroll
    for (int i = 0; i < 6; ++i) {
      const int flat = i * 1024 + lane * 16;
      const int row = flat >> 6, colb = flat & 63;
      const u16* src = (row < 48) ? (qb + (size_t)row * QS + nn)
                                  : (kb + (size_t)(row - 48) * QS + nn);
      gload_lds16((const char*)src + (colb ^ ((row & 3) << 4)), tl + i * 1024);
    }
    asm volatile("s_waitcnt vmcnt(0)" ::: "memory");
    bf16x8 qf[3], kf[3];
#pragma unroll
    for (int f = 0; f < 3; ++f) {
      qf[f] = *(const bf16x8*)(tl + (f * 16 + l15) * 64 + ((lg * 16) ^ swz));
      kf[f] = *(const bf16x8*)(tl + (48 + f * 16 + l15) * 64 + ((lg * 16) ^ swz));
    }
#pragma unroll
    for (int i = 0; i < 3; ++i)
#pragma unroll
      for (int j = 0; j < 3; ++j)
        acc[i][j] = __builtin_amdgcn_mfma_f32_16x16x32_bf16(qf[i], kf[j],
                                                            acc[i][j], 0, 0, 0);
  }
  // in-block reduce over the 4 waves
  {
    float* rw = red + wave * 2304;
#pragma unroll
    for (int i = 0; i < 3; ++i)
#pragma unroll
      for (int j = 0; j < 3; ++j)
#pragma unroll
        for (int r = 0; r < 4; ++r)
          rw[(i * 16 + lg * 4 + r) * 48 + (j * 16 + l15)] = acc[i][j][r];
  }
  __syncthreads();
#pragma unroll
  for (int it = 0; it < 9; ++it) {
    const int p = it * 256 + threadIdx.x;
    const float s = red[p] + red[2304 + p] + red[4608 + p] + red[6912 + p];
    partial[((size_t)bh * 2304 + p) * 32 + g] = s;
  }
}

// ---------------------------------------------------------------------------
// Wide reduction of gram partials: G[bh*2304+p] = sum over 32 chunks.
__global__ __launch_bounds__(256) void reduce_partial_kernel(
    const float* __restrict__ partial, float* __restrict__ G) {
  const int idx = blockIdx.x * 256 + threadIdx.x;  // 0..36863
  const f32x4* pp = (const f32x4*)(partial + (size_t)idx * 32);
  const f32x4 a = (pp[0] + pp[1]) + (pp[2] + pp[3]) +
                  (pp[4] + pp[5]) + (pp[6] + pp[7]);
  G[idx] = a.x + a.y + a.z + a.w;
}

// ---------------------------------------------------------------------------
// Normalize, softmax, fold attn into projection (plain row-major Weff out).
__global__ __launch_bounds__(256) void softmax_weff_kernel(
    const float* __restrict__ Gin, const float* __restrict__ sq,
    const float* __restrict__ temp, const float* __restrict__ wproj,
    u16* __restrict__ weff) {
  __shared__ float G[2304];        // gram -> attn (in place)
  __shared__ float wp[192 * 49];   // wproj slice, pad 49 (odd bank stride)
  __shared__ float nq[48], nk[48];
  const int bh = blockIdx.x, b = bh >> 2, h = bh & 3;
  const int tid = threadIdx.x;
#pragma unroll
  for (int it = 0; it < 36; ++it) {  // load wproj [192][h*48 .. h*48+48)
    const int j = it * 256 + tid;
    const int o = j / 48, c = j - o * 48;
    wp[o * 49 + c] = wproj[o * 192 + h * 48 + c];
  }
#pragma unroll
  for (int it = 0; it < 9; ++it) {
    const int p = it * 256 + tid;
    G[p] = Gin[(size_t)bh * 2304 + p];
  }
  if (tid < 48) {
    nq[tid] = fmaxf(sqrtf(sq[b * 576 + h * 48 + tid]), 1e-12f);
    nk[tid] = fmaxf(sqrtf(sq[b * 576 + 192 + h * 48 + tid]), 1e-12f);
  }
  __syncthreads();
  if (tid < 48) {  // row softmax (48 rows)
    const int r = tid;
    const float inq = temp[h] / nq[r];
    float L[48];
    float mx = -3.4e38f;
#pragma unroll 4
    for (int d = 0; d < 48; ++d) {
      const float v = G[r * 48 + d] * inq / nk[d];
      L[d] = v;
      mx = fmaxf(mx, v);
    }
    float s = 0.f;
#pragma unroll 4
    for (int d = 0; d < 48; ++d) {
      const float e = __expf(L[d] - mx);
      L[d] = e;
      s += e;
    }
    const float inv = 1.f / s;
#pragma unroll 4
    for (int d = 0; d < 48; ++d) G[r * 48 + d] = L[d] * inv;
  }
  __syncthreads();
  if (tid < 192) {  // Weff row o = tid
    const int o = tid;
    f32x4 acc[12];
#pragma unroll
    for (int dv = 0; dv < 12; ++dv) acc[dv] = (f32x4){0.f, 0.f, 0.f, 0.f};
    for (int c = 0; c < 48; ++c) {
      const float w = wp[o * 49 + c];
      const f32x4* at = (const f32x4*)(G + c * 48);  // broadcast reads
#pragma unroll
      for (int dv = 0; dv < 12; ++dv) acc[dv] += w * at[dv];
    }
    u16* op = weff + ((size_t)b * 192 + o) * 192 + h * 48;
#pragma unroll
    for (int g8 = 0; g8 < 6; ++g8) {
      u16x8 ov;
#pragma unroll
      for (int j = 0; j < 8; ++j) {
        const int d = g8 * 8 + j;
        ov[j] = f2bf(acc[d >> 2][d & 3]);
      }
      *(u16x8*)(op + g8 * 8) = ov;
    }
  }
}

// ---------------------------------------------------------------------------
extern "C" void kernel_launch(void* const* d_in, const int* in_sizes, int n_in,
                              void* d_out, int out_size, void* d_ws,
                              size_t ws_size, hipStream_t stream) {
  (void)in_sizes; (void)n_in; (void)out_size; (void)ws_size;
  const float* x      = (const float*)d_in[0];  // [4][192][128][128]
  const float* w_qkv  = (const float*)d_in[1];  // [576][192]
  const float* w_dw   = (const float*)d_in[2];  // [576][9]
  const float* w_proj = (const float*)d_in[3];  // [192][192]
  const float* temp   = (const float*)d_in[4];  // [4]

  char* ws = (char*)d_ws;
  u16*   qkv     = (u16*)ws;                    // 4*576*QS*2 = 75,792,384 B
  float* partial = (float*)(ws + 75792384);     //  4,718,592 B [16][2304][32]
  float* G       = (float*)(ws + 80510976);     //    147,456 B
  float* sq      = (float*)(ws + 80658432);     //      9,216 B
  u16*   Wq      = (u16*)(ws + 80667648);       //    221,184 B [576][192]
  u16*   Weff    = (u16*)(ws + 80888832);       //    294,912 B [4][192][192]

  // w_qkv -> bf16
  convert_w_kernel<<<dim3(432), 256, 0, stream>>>(w_qkv, Wq, 110592);
  // qkv[b][o][n] = sum_c x[c][n]*Wq[o][c]  (fused x-transpose; 9 tiles/wave)
  gemm_bt_kernel<true, true, 9><<<dim3(256, 4), 256, 0, stream>>>(
      x, Wq, qkv, (size_t)192 * 16384, 16384, 0, (size_t)576 * QS, QS);
  // depthwise 3x3 in-place + per-channel sum-of-squares
  dwconv_kernel<<<dim3(576, 4), 256, 0, stream>>>(qkv, w_dw, sq);
  // gram partials: 32 chunk-groups per (b,h), in-block wave reduction
  gram_kernel<<<dim3(32, 16), 256, 0, stream>>>(qkv, partial);
  // wide cross-chunk reduction
  reduce_partial_kernel<<<dim3(144), 256, 0, stream>>>(partial, G);
  // normalize + softmax + fold into projection
  softmax_weff_kernel<<<dim3(16), 256, 0, stream>>>(G, sq, temp, w_proj, Weff);
  // out[b][o][n] = sum_c2 v[c2][n]*Weff[o][c2] (fused v-transpose; 3/wave)
  gemm_bt_kernel<false, false, 3><<<dim3(256, 4), 256, 0, stream>>>(
      qkv + (size_t)384 * QS, Weff, d_out, (size_t)576 * QS, QS,
      (size_t)192 * 192, (size_t)192 * 16384, 16384);
}